// Round 1
// baseline (778.104 us; speedup 1.0000x reference)
//
#include <hip/hip_runtime.h>
#include <hip/hip_bf16.h>

#define N_ATOMS 100000
#define K_NBR   64
#define N_STRUCT 32
#define HID     128
#define N_EDGE  (N_ATOMS * K_NBR)   // 6,400,000

// ---------------------------------------------------------------------------
// Kernel 1: transpose neighbors_index [K, N] -> nbrT [N, K] (LDS tiled)
// ---------------------------------------------------------------------------
__global__ __launch_bounds__(256) void transpose_kernel(
    const int* __restrict__ src, int* __restrict__ dst)
{
    __shared__ int tile[64][65];   // +1 pad: no bank conflicts
    const int n0   = blockIdx.x * 64;
    const int lane = threadIdx.x & 63;
    const int ty   = threadIdx.x >> 6;   // 0..3

    #pragma unroll
    for (int i = 0; i < 16; ++i) {
        int k = i * 4 + ty;
        int n = n0 + lane;
        int v = (n < N_ATOMS) ? src[k * N_ATOMS + n] : 0;  // coalesced read
        tile[k][lane] = v;
    }
    __syncthreads();
    #pragma unroll
    for (int i = 0; i < 16; ++i) {
        int nl = i * 4 + ty;
        int n  = n0 + nl;
        if (n < N_ATOMS) dst[n * 64 + lane] = tile[lane][nl];  // coalesced write
    }
}

// ---------------------------------------------------------------------------
// Kernel 2: per-edge MLP fwd+bwd.
//   thread = edge (n,k); lane = k so one wave = one atom's 64 edges.
//   Computes e = sum_d w2[d]*tanh(p_d), g_c = sum_d W1[c,d]*w2[d]*(1-t^2),
//   stores masked g to grads[N,K,3], wave-reduces masked e -> per_atom[n].
// ---------------------------------------------------------------------------
__global__ __launch_bounds__(256) void edge_kernel(
    const float* __restrict__ x, const int* __restrict__ mask,
    const float* __restrict__ W1, const float* __restrict__ w2,
    float* __restrict__ grads, float* __restrict__ per_atom)
{
    // Stage (W1[0,d], W1[1,d], W1[2,d], w2[d]) as float4 per hidden unit.
    __shared__ float4 sw[HID];
    const int tid = threadIdx.x;
    if (tid < HID)
        sw[tid] = make_float4(W1[tid], W1[HID + tid], W1[2 * HID + tid], w2[tid]);
    __syncthreads();

    const int ei = blockIdx.x * 256 + tid;      // edge id, grid sized exactly
    const float* xp = x + (size_t)ei * 3;
    const float x0 = xp[0], x1 = xp[1], x2 = xp[2];
    const int m = mask[ei];

    float esum = 0.f, g0 = 0.f, g1 = 0.f, g2 = 0.f;

    #pragma unroll 8
    for (int d = 0; d < HID; ++d) {
        float4 w = sw[d];                                   // LDS broadcast
        float p  = fmaf(x0, w.x, fmaf(x1, w.y, x2 * w.z));
        // tanh(p) = 1 - 2/(exp(2p)+1): exact limits at +-inf, ~1e-6 accurate
        float ex = __expf(p + p);
        float r  = __builtin_amdgcn_rcpf(ex + 1.0f);
        float t  = fmaf(-2.0f, r, 1.0f);
        esum = fmaf(t, w.w, esum);
        float q = fmaf(-t, t, 1.0f);                        // 1 - t^2
        float s = q * w.w;
        g0 = fmaf(s, w.x, g0);
        g1 = fmaf(s, w.y, g1);
        g2 = fmaf(s, w.z, g2);
    }

    if (m) { esum = 0.f; g0 = 0.f; g1 = 0.f; g2 = 0.f; }

    float* gp = grads + (size_t)ei * 3;
    gp[0] = g0; gp[1] = g1; gp[2] = g2;

    // wave (= atom) reduction of masked energy
    for (int off = 32; off; off >>= 1)
        esum += __shfl_down(esum, off, 64);
    if ((tid & 63) == 0)
        per_atom[ei >> 6] = esum;
}

// ---------------------------------------------------------------------------
// Kernel 3: forces + preds.
//   wave = atom, lane = k. first = sum_k grads[n,k,:] (already masked),
//   second = sum_k (1-mask)*grads[nbr,pos,:] (random gather).
//   preds: LDS 32-bin block accumulation of per_atom, then global atomics.
// ---------------------------------------------------------------------------
__global__ __launch_bounds__(256) void atom_kernel(
    const float* __restrict__ grads, const int* __restrict__ nbrT,
    const int* __restrict__ pos, const int* __restrict__ mask,
    const int* __restrict__ batch, const float* __restrict__ per_atom,
    float* __restrict__ out)   // out[0:32] preds, out[32:] forces [N,3]
{
    __shared__ float sp[N_STRUCT];
    const int tid = threadIdx.x;
    if (tid < N_STRUCT) sp[tid] = 0.f;
    __syncthreads();

    const int lane = tid & 63;
    const int wa   = tid >> 6;                 // wave in block: 0..3
    const int n    = blockIdx.x * 4 + wa;      // atom
    const bool act = (n < N_ATOMS);

    float f0 = 0.f, f1 = 0.f, f2 = 0.f;
    if (act) {
        const int ei = n * 64 + lane;
        const size_t go = (size_t)ei * 3;
        float a0 = grads[go], a1 = grads[go + 1], a2 = grads[go + 2];  // coalesced
        const int m  = mask[ei];
        const int nb = nbrT[ei];
        const int ps = pos[ei];
        float b0 = 0.f, b1 = 0.f, b2 = 0.f;
        if (!m) {
            const size_t gi = ((size_t)nb * 64 + ps) * 3;   // random gather
            b0 = grads[gi]; b1 = grads[gi + 1]; b2 = grads[gi + 2];
        }
        f0 = a0 - b0; f1 = a1 - b1; f2 = a2 - b2;
    }

    for (int off = 32; off; off >>= 1) {
        f0 += __shfl_down(f0, off, 64);
        f1 += __shfl_down(f1, off, 64);
        f2 += __shfl_down(f2, off, 64);
    }

    if (act && lane == 0) {
        float* fo = out + N_STRUCT + (size_t)n * 3;
        fo[0] = f0; fo[1] = f1; fo[2] = f2;
        atomicAdd(&sp[batch[n]], per_atom[n]);
    }
    __syncthreads();
    if (tid < N_STRUCT) atomicAdd(&out[tid], sp[tid]);
}

// ---------------------------------------------------------------------------
extern "C" void kernel_launch(void* const* d_in, const int* in_sizes, int n_in,
                              void* d_out, int out_size, void* d_ws, size_t ws_size,
                              hipStream_t stream)
{
    const float* x    = (const float*)d_in[0];
    const int*   nidx = (const int*)d_in[1];   // [K, N]
    const int*   npos = (const int*)d_in[2];   // [N, K]
    const int*   mask = (const int*)d_in[3];   // [N, K]
    const int*   bidx = (const int*)d_in[4];   // [N]
    const float* W1   = (const float*)d_in[5]; // [3, HID]
    const float* w2   = (const float*)d_in[6]; // [HID]
    float* out = (float*)d_out;

    char* ws = (char*)d_ws;
    float* grads    = (float*)ws;                                        // N_EDGE*3 f32
    int*   nbrT     = (int*)(ws + (size_t)N_EDGE * 3 * sizeof(float));   // N_EDGE i32
    float* per_atom = (float*)(ws + (size_t)N_EDGE * 3 * sizeof(float)
                                  + (size_t)N_EDGE * sizeof(int));       // N_ATOMS f32

    hipMemsetAsync(out, 0, N_STRUCT * sizeof(float), stream);

    hipLaunchKernelGGL(transpose_kernel, dim3((N_ATOMS + 63) / 64), dim3(256),
                       0, stream, nidx, nbrT);
    hipLaunchKernelGGL(edge_kernel, dim3(N_EDGE / 256), dim3(256),
                       0, stream, x, mask, W1, w2, grads, per_atom);
    hipLaunchKernelGGL(atom_kernel, dim3((N_ATOMS + 3) / 4), dim3(256),
                       0, stream, grads, nbrT, npos, mask, bidx, per_atom, out);
}

// Round 2
// 479.553 us; speedup vs baseline: 1.6226x; 1.6226x over previous
//
#include <hip/hip_runtime.h>
#include <hip/hip_bf16.h>

#define N_ATOMS 100000
#define K_NBR   64
#define N_STRUCT 32
#define HID     128
#define N_EDGE  (N_ATOMS * K_NBR)     // 6,400,000
#define NBLK_E  (N_EDGE / 256)        // 25,000 (exact)

typedef unsigned int uint;

__device__ __forceinline__ uint bf_rne(float f) {        // fp32 -> bf16 bits (RNE)
    uint u = __float_as_uint(f);
    return (u + 0x7fffu + ((u >> 16) & 1u)) >> 16;
}
__device__ __forceinline__ float ubf_lo(uint u) { return __uint_as_float(u << 16); }
__device__ __forceinline__ float ubf_hi(uint u) { return __uint_as_float(u & 0xffff0000u); }

// ---------------------------------------------------------------------------
// Prep: pack weights. pw4[d] = {2*W1[0,d], 2*W1[1,d], 2*W1[2,d], w2[d]}
//       gw4[d] = {4*w2*W1[0,d], 4*w2*W1[1,d], 4*w2*W1[2,d], 0}; sumw2 scalar.
// tanh identities: ex=e^{2p}; r=1/(ex+1); t=1-2r; e=Σw2·t = Σw2 - 2Σw2·r;
//                  1-t^2 = 4·ex·r^2.
// ---------------------------------------------------------------------------
__global__ void prep_kernel(const float* __restrict__ W1, const float* __restrict__ w2,
                            float4* __restrict__ pw4, float4* __restrict__ gw4,
                            float* __restrict__ sumw2)
{
    int d = threadIdx.x;                         // 128 threads
    float w0 = W1[d], w1 = W1[HID + d], wc = W1[2 * HID + d], wv = w2[d];
    pw4[d] = make_float4(2.f * w0, 2.f * w1, 2.f * wc, wv);
    gw4[d] = make_float4(4.f * wv * w0, 4.f * wv * w1, 4.f * wv * wc, 0.f);
    float v = wv;
    for (int off = 32; off; off >>= 1) v += __shfl_down(v, off, 64);
    __shared__ float sw_[2];
    if ((threadIdx.x & 63) == 0) sw_[threadIdx.x >> 6] = v;
    __syncthreads();
    if (threadIdx.x == 0) sumw2[0] = sw_[0] + sw_[1];
}

// ---------------------------------------------------------------------------
// Compaction (deterministic, no global atomics):
//   K1: per-block unmasked count.  K2: single-block exclusive scan.
//   K3: scatter edge ids compacted.
// ---------------------------------------------------------------------------
__global__ __launch_bounds__(256) void count_kernel(const int* __restrict__ mask,
                                                    int* __restrict__ bc)
{
    int ei = blockIdx.x * 256 + threadIdx.x;
    unsigned long long bal = __ballot(mask[ei] == 0);
    __shared__ int c[4];
    if ((threadIdx.x & 63) == 0) c[threadIdx.x >> 6] = __popcll(bal);
    __syncthreads();
    if (threadIdx.x == 0) bc[blockIdx.x] = c[0] + c[1] + c[2] + c[3];
}

__global__ void scan_kernel(const int* __restrict__ bc, int* __restrict__ bb,
                            int* __restrict__ cnt)
{
    __shared__ int ps[256];
    const int CH = (NBLK_E + 255) / 256;         // 98
    int tid = threadIdx.x;
    int s = 0;
    for (int j = 0; j < CH; ++j) {
        int idx = tid * CH + j;
        if (idx < NBLK_E) s += bc[idx];
    }
    ps[tid] = s;
    __syncthreads();
    if (tid == 0) {
        int acc = 0;
        for (int i = 0; i < 256; ++i) { int v = ps[i]; ps[i] = acc; acc += v; }
        cnt[0] = acc;
    }
    __syncthreads();
    int base = ps[tid];
    for (int j = 0; j < CH; ++j) {
        int idx = tid * CH + j;
        if (idx < NBLK_E) { bb[idx] = base; base += bc[idx]; }
    }
}

__global__ __launch_bounds__(256) void scatter_kernel(const int* __restrict__ mask,
                                                      const int* __restrict__ bb,
                                                      int* __restrict__ ids)
{
    int tid = threadIdx.x, lane = tid & 63, w = tid >> 6;
    int ei = blockIdx.x * 256 + tid;
    int un = (mask[ei] == 0);
    unsigned long long bal = __ballot(un);
    __shared__ int woff[4];
    if (lane == 0) woff[w] = __popcll(bal);
    __syncthreads();
    int base = bb[blockIdx.x];
    for (int i = 0; i < w; ++i) base += woff[i];
    int pre = __popcll(bal & ((1ull << lane) - 1ull));
    if (un) ids[base + pre] = ei;
}

// ---------------------------------------------------------------------------
// Edge MLP over compacted unmasked edges. Writes bf16x3-packed grads (uint2)
// and per-block 32-bin energy partials (no global atomics).
// ---------------------------------------------------------------------------
__global__ __launch_bounds__(256) void edge_mlp(
    const float* __restrict__ x, const int* __restrict__ ids,
    const int* __restrict__ cntp, const int* __restrict__ batch,
    const float4* __restrict__ pw4, const float4* __restrict__ gw4,
    const float* __restrict__ sumw2p,
    uint2* __restrict__ gr8, float* __restrict__ part)
{
    __shared__ float sp[N_STRUCT];
    int tid = threadIdx.x;
    if (tid < N_STRUCT) sp[tid] = 0.f;
    __syncthreads();

    int i = blockIdx.x * 256 + tid;
    int cnt = cntp[0];
    if (i < cnt) {
        int eid = ids[i];
        const float* xp = x + (size_t)eid * 3;
        float x0 = xp[0], x1 = xp[1], x2 = xp[2];
        float rsum = 0.f, g0 = 0.f, g1 = 0.f, g2 = 0.f;
        #pragma unroll 8
        for (int d = 0; d < HID; ++d) {
            float4 w  = pw4[d];                          // wave-uniform -> s_load
            float4 gw = gw4[d];
            float pd = fmaf(x0, w.x, fmaf(x1, w.y, x2 * w.z));   // = 2p
            float ex = __expf(pd);                               // e^{2p}
            float r  = __builtin_amdgcn_rcpf(ex + 1.f);
            rsum = fmaf(w.w, r, rsum);
            float s2 = ex * r; s2 *= r;                          // (1-t^2)/4
            g0 = fmaf(s2, gw.x, g0);
            g1 = fmaf(s2, gw.y, g1);
            g2 = fmaf(s2, gw.z, g2);
        }
        float e = fmaf(-2.f, rsum, sumw2p[0]);
        uint lo = bf_rne(g0) | (bf_rne(g1) << 16);
        uint hi = bf_rne(g2);
        gr8[eid] = make_uint2(lo, hi);
        atomicAdd(&sp[batch[eid >> 6]], e);
    }
    __syncthreads();
    if (tid < N_STRUCT) part[(size_t)tid * NBLK_E + blockIdx.x] = sp[tid];
}

__global__ __launch_bounds__(256) void reduce_preds(const float* __restrict__ part,
                                                    float* __restrict__ out)
{
    int s = blockIdx.x, tid = threadIdx.x;
    float v = 0.f;
    for (int i = tid; i < NBLK_E; i += 256) v += part[(size_t)s * NBLK_E + i];
    for (int off = 32; off; off >>= 1) v += __shfl_down(v, off, 64);
    __shared__ float sv[4];
    if ((tid & 63) == 0) sv[tid >> 6] = v;
    __syncthreads();
    if (tid == 0) out[s] = sv[0] + sv[1] + sv[2] + sv[3];
}

// ---------------------------------------------------------------------------
// Transpose neighbors_index [K, N] -> nbrT [N, K]  (runs AFTER edge_mlp;
// nbrT aliases the ids buffer)
// ---------------------------------------------------------------------------
__global__ __launch_bounds__(256) void transpose_kernel(
    const int* __restrict__ src, int* __restrict__ dst)
{
    __shared__ int tile[64][65];
    const int n0 = blockIdx.x * 64;
    const int lane = threadIdx.x & 63;
    const int ty = threadIdx.x >> 6;
    #pragma unroll
    for (int i = 0; i < 16; ++i) {
        int k = i * 4 + ty, n = n0 + lane;
        tile[k][lane] = (n < N_ATOMS) ? src[k * N_ATOMS + n] : 0;
    }
    __syncthreads();
    #pragma unroll
    for (int i = 0; i < 16; ++i) {
        int nl = i * 4 + ty, n = n0 + nl;
        if (n < N_ATOMS) dst[n * 64 + lane] = tile[lane][nl];
    }
}

// ---------------------------------------------------------------------------
// Forces: wave = atom, lane = k. first from coalesced gr8 read (masked are 0),
// second from single aligned 8B gather. No atomics.
// ---------------------------------------------------------------------------
__global__ __launch_bounds__(256) void atom_kernel(
    const uint2* __restrict__ gr8, const int* __restrict__ nbrT,
    const int* __restrict__ pos, const int* __restrict__ mask,
    float* __restrict__ out)
{
    int tid = threadIdx.x, lane = tid & 63, w = tid >> 6;
    int n = blockIdx.x * 4 + w;
    int ei = n * 64 + lane;

    uint2 a = gr8[ei];                                   // coalesced 8B
    int m  = mask[ei];
    int nb = nbrT[ei];
    int ps = pos[ei];
    uint2 b = make_uint2(0u, 0u);
    if (!m) b = gr8[(size_t)nb * 64 + ps];               // aligned 8B gather

    float f0 = ubf_lo(a.x) - ubf_lo(b.x);
    float f1 = ubf_hi(a.x) - ubf_hi(b.x);
    float f2 = ubf_lo(a.y) - ubf_lo(b.y);

    for (int off = 32; off; off >>= 1) {
        f0 += __shfl_down(f0, off, 64);
        f1 += __shfl_down(f1, off, 64);
        f2 += __shfl_down(f2, off, 64);
    }
    if (lane == 0) {
        float* fo = out + N_STRUCT + (size_t)n * 3;
        fo[0] = f0; fo[1] = f1; fo[2] = f2;
    }
}

// ---------------------------------------------------------------------------
extern "C" void kernel_launch(void* const* d_in, const int* in_sizes, int n_in,
                              void* d_out, int out_size, void* d_ws, size_t ws_size,
                              hipStream_t stream)
{
    const float* x    = (const float*)d_in[0];
    const int*   nidx = (const int*)d_in[1];   // [K, N]
    const int*   npos = (const int*)d_in[2];   // [N, K]
    const int*   mask = (const int*)d_in[3];   // [N, K]
    const int*   bidx = (const int*)d_in[4];   // [N]
    const float* W1   = (const float*)d_in[5]; // [3, HID]
    const float* w2   = (const float*)d_in[6]; // [HID]
    float* out = (float*)d_out;

    char* ws = (char*)d_ws;
    uint2* gr8  = (uint2*)ws;                                  // 51.2 MB
    int*   ids  = (int*)(ws + (size_t)N_EDGE * 8);             // 25.6 MB (aliased by nbrT)
    int*   nbrT = ids;
    float* part = (float*)(ws + (size_t)N_EDGE * 8 + (size_t)N_EDGE * 4);        // 3.2 MB
    char*  tail = ws + (size_t)N_EDGE * 8 + (size_t)N_EDGE * 4
                     + (size_t)N_STRUCT * NBLK_E * 4;
    int*    bc    = (int*)tail;                                // 100 KB
    int*    bb    = (int*)(tail + NBLK_E * 4);                 // 100 KB
    float4* pw4   = (float4*)(tail + 2 * NBLK_E * 4);          // 2 KB
    float4* gw4   = (float4*)(tail + 2 * NBLK_E * 4 + HID * 16);
    float*  sumw2 = (float*)(tail + 2 * NBLK_E * 4 + 2 * HID * 16);
    int*    cnt   = (int*)(tail + 2 * NBLK_E * 4 + 2 * HID * 16 + 16);

    hipMemsetAsync(gr8, 0, (size_t)N_EDGE * 8, stream);        // masked grads = 0

    hipLaunchKernelGGL(prep_kernel, dim3(1), dim3(128), 0, stream, W1, w2, pw4, gw4, sumw2);
    hipLaunchKernelGGL(count_kernel, dim3(NBLK_E), dim3(256), 0, stream, mask, bc);
    hipLaunchKernelGGL(scan_kernel, dim3(1), dim3(256), 0, stream, bc, bb, cnt);
    hipLaunchKernelGGL(scatter_kernel, dim3(NBLK_E), dim3(256), 0, stream, mask, bb, ids);
    hipLaunchKernelGGL(edge_mlp, dim3(NBLK_E), dim3(256), 0, stream,
                       x, ids, cnt, bidx, pw4, gw4, sumw2, gr8, part);
    hipLaunchKernelGGL(transpose_kernel, dim3((N_ATOMS + 63) / 64), dim3(256),
                       0, stream, nidx, nbrT);                 // after edge_mlp: alias safe
    hipLaunchKernelGGL(atom_kernel, dim3(N_ATOMS / 4), dim3(256), 0, stream,
                       gr8, nbrT, npos, mask, out);
    hipLaunchKernelGGL(reduce_preds, dim3(N_STRUCT), dim3(256), 0, stream, part, out);
}

// Round 3
// 470.399 us; speedup vs baseline: 1.6541x; 1.0195x over previous
//
#include <hip/hip_runtime.h>
#include <hip/hip_bf16.h>

#define N_ATOMS 100000
#define K_NBR   64
#define N_STRUCT 32
#define HID     128
#define N_EDGE  (N_ATOMS * K_NBR)     // 6,400,000
#define NBLK_E  (N_EDGE / 256)        // 25,000 (exact)

typedef unsigned int uint;

#if __has_builtin(__builtin_amdgcn_exp2f)
#define EXP2(v) __builtin_amdgcn_exp2f(v)
#else
#define EXP2(v) __expf((v) * 0.69314718056f)
#endif

__device__ __forceinline__ uint bf_rne(float f) {        // fp32 -> bf16 bits (RNE)
    uint u = __float_as_uint(f);
    return (u + 0x7fffu + ((u >> 16) & 1u)) >> 16;
}
__device__ __forceinline__ float ubf_lo(uint u) { return __uint_as_float(u << 16); }
__device__ __forceinline__ float ubf_hi(uint u) { return __uint_as_float(u & 0xffff0000u); }

// ---------------------------------------------------------------------------
// count + prep (block 0 only packs weights):
//   pw4[d] = {2*log2e*W1[0,d], 2*log2e*W1[1,d], 2*log2e*W1[2,d], w2[d]}
//   gw4[d] = {4*w2*W1[0,d],    4*w2*W1[1,d],    4*w2*W1[2,d],    0}
// identities: ex = e^{2p} = exp2(x·pw); r = 1/(1+ex); e_d = w2(1-2r);
//             (1-t^2)/4 = r - r^2.
// ---------------------------------------------------------------------------
__global__ __launch_bounds__(256) void count_prep(
    const int* __restrict__ mask, int* __restrict__ bc,
    const float* __restrict__ W1, const float* __restrict__ w2,
    float4* __restrict__ pw4, float4* __restrict__ gw4, float* __restrict__ sumw2)
{
    const int tid = threadIdx.x;
    int ei = blockIdx.x * 256 + tid;
    unsigned long long bal = __ballot(mask[ei] == 0);
    __shared__ int c[4];
    if ((tid & 63) == 0) c[tid >> 6] = __popcll(bal);
    __syncthreads();
    if (tid == 0) bc[blockIdx.x] = c[0] + c[1] + c[2] + c[3];

    if (blockIdx.x == 0) {
        const float L2E2 = 2.885390082f;   // 2*log2(e)
        float wv = 0.f;
        if (tid < HID) {
            float w0 = W1[tid], w1 = W1[HID + tid], wc = W1[2 * HID + tid];
            wv = w2[tid];
            pw4[tid] = make_float4(L2E2 * w0, L2E2 * w1, L2E2 * wc, wv);
            gw4[tid] = make_float4(4.f * wv * w0, 4.f * wv * w1, 4.f * wv * wc, 0.f);
        }
        for (int off = 32; off; off >>= 1) wv += __shfl_down(wv, off, 64);
        __shared__ float sw_[4];
        if ((tid & 63) == 0) sw_[tid >> 6] = wv;
        __syncthreads();
        if (tid == 0) sumw2[0] = sw_[0] + sw_[1];   // only waves 0,1 hold w2
    }
}

__global__ void scan_kernel(const int* __restrict__ bc, int* __restrict__ bb,
                            int* __restrict__ cnt)
{
    __shared__ int ps[256];
    const int CH = (NBLK_E + 255) / 256;         // 98
    int tid = threadIdx.x;
    int s = 0;
    for (int j = 0; j < CH; ++j) {
        int idx = tid * CH + j;
        if (idx < NBLK_E) s += bc[idx];
    }
    ps[tid] = s;
    __syncthreads();
    if (tid == 0) {
        int acc = 0;
        for (int i = 0; i < 256; ++i) { int v = ps[i]; ps[i] = acc; acc += v; }
        cnt[0] = acc;
    }
    __syncthreads();
    int base = ps[tid];
    for (int j = 0; j < CH; ++j) {
        int idx = tid * CH + j;
        if (idx < NBLK_E) { bb[idx] = base; base += bc[idx]; }
    }
}

// scatter compacted ids AND zero gr8 at masked edges (replaces 51MB memset)
__global__ __launch_bounds__(256) void scatter_zero(
    const int* __restrict__ mask, const int* __restrict__ bb,
    int* __restrict__ ids, uint2* __restrict__ gr8)
{
    int tid = threadIdx.x, lane = tid & 63, w = tid >> 6;
    int ei = blockIdx.x * 256 + tid;
    int un = (mask[ei] == 0);
    unsigned long long bal = __ballot(un);
    __shared__ int woff[4];
    if (lane == 0) woff[w] = __popcll(bal);
    __syncthreads();
    int base = bb[blockIdx.x];
    for (int i = 0; i < w; ++i) base += woff[i];
    int pre = __popcll(bal & ((1ull << lane) - 1ull));
    if (un) ids[base + pre] = ei;
    else    gr8[ei] = make_uint2(0u, 0u);
}

// ---------------------------------------------------------------------------
// Edge MLP over compacted unmasked edges; 4-way ganged reciprocal.
// ---------------------------------------------------------------------------
__global__ __launch_bounds__(256) void edge_mlp(
    const float* __restrict__ x, const int* __restrict__ ids,
    const int* __restrict__ cntp, const int* __restrict__ batch,
    const float4* __restrict__ pw4, const float4* __restrict__ gw4,
    const float* __restrict__ sumw2p,
    uint2* __restrict__ gr8, float* __restrict__ part)
{
    __shared__ float sp[N_STRUCT];
    int tid = threadIdx.x;
    if (tid < N_STRUCT) sp[tid] = 0.f;
    __syncthreads();

    int i = blockIdx.x * 256 + tid;
    int cnt = cntp[0];
    if (i < cnt) {
        int eid = ids[i];
        const float* xp = x + (size_t)eid * 3;
        float x0 = xp[0], x1 = xp[1], x2 = xp[2];
        float rsum = 0.f, g0 = 0.f, g1 = 0.f, g2 = 0.f;
        for (int d = 0; d < HID; d += 4) {
            float4 wa = pw4[d], wb = pw4[d + 1], wc = pw4[d + 2], wd = pw4[d + 3];
            float4 Ga = gw4[d], Gb = gw4[d + 1], Gc = gw4[d + 2], Gd = gw4[d + 3];
            float ea = EXP2(fmaf(x0, wa.x, fmaf(x1, wa.y, x2 * wa.z)));
            float eb = EXP2(fmaf(x0, wb.x, fmaf(x1, wb.y, x2 * wb.z)));
            float ec = EXP2(fmaf(x0, wc.x, fmaf(x1, wc.y, x2 * wc.z)));
            float ed = EXP2(fmaf(x0, wd.x, fmaf(x1, wd.y, x2 * wd.z)));
            float aa = ea + 1.f, ab = eb + 1.f, ac = ec + 1.f, ad = ed + 1.f;
            float pab = aa * ab, pcd = ac * ad;
            float q   = __builtin_amdgcn_rcpf(pab * pcd);     // one rcp per 4 d
            float qab = q * pcd, qcd = q * pab;
            float ra = qab * ab, rb = qab * aa, rc = qcd * ad, rd = qcd * ac;
            rsum = fmaf(wa.w, ra, rsum);
            rsum = fmaf(wb.w, rb, rsum);
            rsum = fmaf(wc.w, rc, rsum);
            rsum = fmaf(wd.w, rd, rsum);
            float sa = fmaf(-ra, ra, ra);                     // r - r^2 = (1-t^2)/4
            float sb = fmaf(-rb, rb, rb);
            float sc = fmaf(-rc, rc, rc);
            float sd = fmaf(-rd, rd, rd);
            g0 = fmaf(sa, Ga.x, g0); g1 = fmaf(sa, Ga.y, g1); g2 = fmaf(sa, Ga.z, g2);
            g0 = fmaf(sb, Gb.x, g0); g1 = fmaf(sb, Gb.y, g1); g2 = fmaf(sb, Gb.z, g2);
            g0 = fmaf(sc, Gc.x, g0); g1 = fmaf(sc, Gc.y, g1); g2 = fmaf(sc, Gc.z, g2);
            g0 = fmaf(sd, Gd.x, g0); g1 = fmaf(sd, Gd.y, g1); g2 = fmaf(sd, Gd.z, g2);
        }
        float e = fmaf(-2.f, rsum, sumw2p[0]);
        uint lo = bf_rne(g0) | (bf_rne(g1) << 16);
        uint hi = bf_rne(g2);
        gr8[eid] = make_uint2(lo, hi);
        atomicAdd(&sp[batch[eid >> 6]], e);
    }
    __syncthreads();
    if (tid < N_STRUCT) part[(size_t)tid * NBLK_E + blockIdx.x] = sp[tid];
}

// ---------------------------------------------------------------------------
// Transpose nidx [K,N] and fuse with pos/mask -> gidx[n,k] = m ? -1 : nb*64+ps
// (gidx aliases ids; runs AFTER edge_mlp)
// ---------------------------------------------------------------------------
__global__ __launch_bounds__(256) void transpose_gidx(
    const int* __restrict__ src, const int* __restrict__ pos,
    const int* __restrict__ mask, int* __restrict__ gidx)
{
    __shared__ int tile[64][65];
    const int n0 = blockIdx.x * 64;
    const int lane = threadIdx.x & 63;
    const int ty = threadIdx.x >> 6;
    #pragma unroll
    for (int i = 0; i < 16; ++i) {
        int k = i * 4 + ty, n = n0 + lane;
        tile[k][lane] = (n < N_ATOMS) ? src[k * N_ATOMS + n] : 0;
    }
    __syncthreads();
    #pragma unroll
    for (int i = 0; i < 16; ++i) {
        int nl = i * 4 + ty, n = n0 + nl;
        if (n < N_ATOMS) {
            int ei = n * 64 + lane;
            int nb = tile[lane][nl];
            int g  = (mask[ei] != 0) ? -1 : (nb * 64 + pos[ei]);
            gidx[ei] = g;
        }
    }
}

// ---------------------------------------------------------------------------
// Forces (2 atoms per wave, 2 outstanding gathers) + preds reduce in blocks 0..31
// ---------------------------------------------------------------------------
__global__ __launch_bounds__(256) void atom_kernel(
    const uint2* __restrict__ gr8, const int* __restrict__ gidx,
    const float* __restrict__ part, float* __restrict__ out)
{
    int tid = threadIdx.x, lane = tid & 63, w = tid >> 6;
    int nA = blockIdx.x * 8 + w * 2;          // wave handles atoms nA, nA+1
    int eiA = nA * 64 + lane;
    int eiB = eiA + 64;

    int gA = gidx[eiA], gB = gidx[eiB];
    uint2 aA = gr8[eiA], aB = gr8[eiB];       // coalesced; masked entries are 0
    uint2 bA = make_uint2(0u, 0u), bB = make_uint2(0u, 0u);
    if (gA >= 0) bA = gr8[gA];                // aligned 8B random gather
    if (gB >= 0) bB = gr8[gB];

    float fA0 = ubf_lo(aA.x) - ubf_lo(bA.x);
    float fA1 = ubf_hi(aA.x) - ubf_hi(bA.x);
    float fA2 = ubf_lo(aA.y) - ubf_lo(bA.y);
    float fB0 = ubf_lo(aB.x) - ubf_lo(bB.x);
    float fB1 = ubf_hi(aB.x) - ubf_hi(bB.x);
    float fB2 = ubf_lo(aB.y) - ubf_lo(bB.y);

    for (int off = 32; off; off >>= 1) {
        fA0 += __shfl_down(fA0, off, 64);
        fA1 += __shfl_down(fA1, off, 64);
        fA2 += __shfl_down(fA2, off, 64);
        fB0 += __shfl_down(fB0, off, 64);
        fB1 += __shfl_down(fB1, off, 64);
        fB2 += __shfl_down(fB2, off, 64);
    }
    if (lane == 0) {
        float* fo = out + N_STRUCT + (size_t)nA * 3;
        fo[0] = fA0; fo[1] = fA1; fo[2] = fA2;
        fo[3] = fB0; fo[4] = fB1; fo[5] = fB2;
    }

    if (blockIdx.x < N_STRUCT) {              // fused preds reduction
        int s = blockIdx.x;
        float v = 0.f;
        for (int i = tid; i < NBLK_E; i += 256) v += part[(size_t)s * NBLK_E + i];
        for (int off = 32; off; off >>= 1) v += __shfl_down(v, off, 64);
        __shared__ float sv[4];
        if (lane == 0) sv[w] = v;
        __syncthreads();
        if (tid == 0) out[s] = sv[0] + sv[1] + sv[2] + sv[3];
    }
}

// ---------------------------------------------------------------------------
extern "C" void kernel_launch(void* const* d_in, const int* in_sizes, int n_in,
                              void* d_out, int out_size, void* d_ws, size_t ws_size,
                              hipStream_t stream)
{
    const float* x    = (const float*)d_in[0];
    const int*   nidx = (const int*)d_in[1];   // [K, N]
    const int*   npos = (const int*)d_in[2];   // [N, K]
    const int*   mask = (const int*)d_in[3];   // [N, K]
    const int*   bidx = (const int*)d_in[4];   // [N]
    const float* W1   = (const float*)d_in[5]; // [3, HID]
    const float* w2   = (const float*)d_in[6]; // [HID]
    float* out = (float*)d_out;

    char* ws = (char*)d_ws;
    uint2* gr8  = (uint2*)ws;                                  // 51.2 MB
    int*   ids  = (int*)(ws + (size_t)N_EDGE * 8);             // 25.6 MB (aliased by gidx)
    int*   gidx = ids;
    float* part = (float*)(ws + (size_t)N_EDGE * 8 + (size_t)N_EDGE * 4);   // 3.2 MB
    char*  tail = ws + (size_t)N_EDGE * 8 + (size_t)N_EDGE * 4
                     + (size_t)N_STRUCT * NBLK_E * 4;
    int*    bc    = (int*)tail;                                // 100 KB
    int*    bb    = (int*)(tail + NBLK_E * 4);                 // 100 KB
    float4* pw4   = (float4*)(tail + 2 * NBLK_E * 4);          // 2 KB
    float4* gw4   = (float4*)(tail + 2 * NBLK_E * 4 + HID * 16);
    float*  sumw2 = (float*)(tail + 2 * NBLK_E * 4 + 2 * HID * 16);
    int*    cnt   = (int*)(tail + 2 * NBLK_E * 4 + 2 * HID * 16 + 16);

    hipLaunchKernelGGL(count_prep, dim3(NBLK_E), dim3(256), 0, stream,
                       mask, bc, W1, w2, pw4, gw4, sumw2);
    hipLaunchKernelGGL(scan_kernel, dim3(1), dim3(256), 0, stream, bc, bb, cnt);
    hipLaunchKernelGGL(scatter_zero, dim3(NBLK_E), dim3(256), 0, stream,
                       mask, bb, ids, gr8);
    hipLaunchKernelGGL(edge_mlp, dim3(NBLK_E), dim3(256), 0, stream,
                       x, ids, cnt, bidx, pw4, gw4, sumw2, gr8, part);
    hipLaunchKernelGGL(transpose_gidx, dim3((N_ATOMS + 63) / 64), dim3(256),
                       0, stream, nidx, npos, mask, gidx);     // after edge_mlp: alias safe
    hipLaunchKernelGGL(atom_kernel, dim3(N_ATOMS / 8), dim3(256), 0, stream,
                       gr8, gidx, part, out);
}